// Round 8
// baseline (66.207 us; speedup 1.0000x reference)
//
#include <hip/hip_runtime.h>

using u32 = unsigned int;

typedef __attribute__((ext_vector_type(8))) _Float16 f16x8;
typedef __attribute__((ext_vector_type(4))) float    f32x4;

// ---------------------------------------------------------------------------
// prep: WcatT[n][kk] = s(i,kb) * W[c][(i^kb)*256 + u]   (f16, 1024x1024)
// sign bits packed: bit (4*i + kb) of 0x3950
// ---------------------------------------------------------------------------
__global__ __launch_bounds__(256) void build_wcatT(const float* __restrict__ W,
                                                   _Float16* __restrict__ Wt) {
    int t  = blockIdx.x * 256 + threadIdx.x;
    int n  = t >> 10, kk = t & 1023;
    int kb = n >> 8,  u  = n & 255;
    int i  = kk >> 8, c  = kk & 255;
    int j  = i ^ kb;
    float v = W[c * 1024 + j * 256 + u];
    if ((0x3950u >> (i * 4 + kb)) & 1u) v = -v;
    Wt[t] = (_Float16)v;
}

// ---------------------------------------------------------------------------
// GEMM, A staged as RAW F32 via global_load_lds (no reg round-trip, no cast
// kernel); f32->f16 conversion happens in the LDS->reg fragment read path.
//   M=16384 N=1024 K=1024.  BM=256, BN=128, BK=64.
//   2 LDS buffers x (A-f32 64KB + B-f16 16KB) = 160 KiB exactly.
//   8 waves (4M x 2N, 64x64 out each, acc[4][4]).  16 K-tiles.
//   Per tile: stage(t+1) at TOP -> 64 MFMA (2 setprio clusters) ->
//             vmcnt(0) at BOTTOM (covered by the whole MFMA phase) -> barrier.
//   Grid 512 @ 1 block/CU: two passes; pass-2 prologue overlaps pass-1
//   epilogue (C-write overlap).
// Swizzles (both-sides): A rows = 16 chunks of 16B, phys = log ^ (row&15);
//                        B rows =  8 chunks of 16B, phys = log ^ (row&7).
// ---------------------------------------------------------------------------
__device__ __forceinline__ void async16(const void* g, void* l) {
    __builtin_amdgcn_global_load_lds((const __attribute__((address_space(1))) u32*)g,
                                     (__attribute__((address_space(3))) u32*)l,
                                     16, 0, 0);
}

#define BARRIER() do { asm volatile("" ::: "memory"); \
                       __builtin_amdgcn_s_barrier(); \
                       asm volatile("" ::: "memory"); } while (0)

#define VMW(n)  asm volatile("s_waitcnt vmcnt(" #n ")" ::: "memory")

#define MFMA(av, bv, c) __builtin_amdgcn_mfma_f32_16x16x32_f16(av, bv, c, 0, 0, 0)

#define MM16() do { \
    __builtin_amdgcn_s_setprio(1); \
    acc[0][0]=MFMA(a0,b0,acc[0][0]); acc[0][1]=MFMA(a0,b1,acc[0][1]); \
    acc[0][2]=MFMA(a0,b2,acc[0][2]); acc[0][3]=MFMA(a0,b3,acc[0][3]); \
    acc[1][0]=MFMA(a1,b0,acc[1][0]); acc[1][1]=MFMA(a1,b1,acc[1][1]); \
    acc[1][2]=MFMA(a1,b2,acc[1][2]); acc[1][3]=MFMA(a1,b3,acc[1][3]); \
    acc[2][0]=MFMA(a2,b0,acc[2][0]); acc[2][1]=MFMA(a2,b1,acc[2][1]); \
    acc[2][2]=MFMA(a2,b2,acc[2][2]); acc[2][3]=MFMA(a2,b3,acc[2][3]); \
    acc[3][0]=MFMA(a3,b0,acc[3][0]); acc[3][1]=MFMA(a3,b1,acc[3][1]); \
    acc[3][2]=MFMA(a3,b2,acc[3][2]); acc[3][3]=MFMA(a3,b3,acc[3][3]); \
    __builtin_amdgcn_s_setprio(0); \
    __builtin_amdgcn_sched_barrier(0); \
} while (0)

// stage A K-tile U (f32, 64KB) into buffer at f32-offset BO: 8 async16/thread
#define ISSUE_A(U, BO) do { \
    const float* _b = pA + (size_t)((U) >> 2) * 4194304 + ((U) & 3) * 64; \
    float* _d = ldsf + (BO) + tid * 4; \
    async16(_b,         _d);         async16(_b +  8192, _d + 2048); \
    async16(_b + 16384, _d + 4096);  async16(_b + 24576, _d + 6144); \
    async16(_b + 32768, _d + 8192);  async16(_b + 40960, _d + 10240); \
    async16(_b + 49152, _d + 12288); async16(_b + 57344, _d + 14336); \
} while (0)

// stage B K-tile U (f16, 16KB) into buffer at f32-offset BO: 2 async16/thread
#define STAGE_B(U, BO) do { \
    const _Float16* _s = gB + (U) * 64; \
    _Float16* _d = (_Float16*)(ldsf + (BO) + 16384) + tid * 8; \
    async16(_s, _d);  async16(_s + 65536, _d + 4096); \
} while (0)

// read A fragment F (m-frag) at chunk offsets C0/C1, cvt f32->f16
#define LDA(dst, Ab, F, C0, C1) do { \
    f32x4 _q0 = *(const f32x4*)((Ab) + aRowBase + (F) * 1024 + (C0)); \
    f32x4 _q1 = *(const f32x4*)((Ab) + aRowBase + (F) * 1024 + (C1)); \
    dst[0]=(_Float16)_q0[0]; dst[1]=(_Float16)_q0[1]; \
    dst[2]=(_Float16)_q0[2]; dst[3]=(_Float16)_q0[3]; \
    dst[4]=(_Float16)_q1[0]; dst[5]=(_Float16)_q1[1]; \
    dst[6]=(_Float16)_q1[2]; dst[7]=(_Float16)_q1[3]; \
} while (0)

#define TILE(T, DO_STAGE, GATE) do { \
    const int _bo = ((T) & 1) * 20480; \
    if (DO_STAGE) { ISSUE_A((T) + 1, _bo ^ 20480); STAGE_B((T) + 1, _bo ^ 20480); } \
    const float* Ab = ldsf + _bo; \
    const _Float16* Bb = (const _Float16*)(Ab + 16384); \
    f16x8 a0, a1, a2, a3, b0, b1, b2, b3; \
    LDA(a0, Ab, 0, ac00, ac01); LDA(a1, Ab, 1, ac00, ac01); \
    LDA(a2, Ab, 2, ac00, ac01); LDA(a3, Ab, 3, ac00, ac01); \
    b0 = *(const f16x8*)(Bb + bRowBase + bc0); \
    b1 = *(const f16x8*)(Bb + bRowBase + 1024 + bc0); \
    b2 = *(const f16x8*)(Bb + bRowBase + 2048 + bc0); \
    b3 = *(const f16x8*)(Bb + bRowBase + 3072 + bc0); \
    MM16(); \
    LDA(a0, Ab, 0, ac10, ac11); LDA(a1, Ab, 1, ac10, ac11); \
    LDA(a2, Ab, 2, ac10, ac11); LDA(a3, Ab, 3, ac10, ac11); \
    b0 = *(const f16x8*)(Bb + bRowBase + bc1); \
    b1 = *(const f16x8*)(Bb + bRowBase + 1024 + bc1); \
    b2 = *(const f16x8*)(Bb + bRowBase + 2048 + bc1); \
    b3 = *(const f16x8*)(Bb + bRowBase + 3072 + bc1); \
    MM16(); \
    GATE; \
    BARRIER(); \
} while (0)

__global__ __launch_bounds__(512, 2) void ga_gemm(const float* __restrict__ A,    // x f32
                                                  const _Float16* __restrict__ Bt,// WcatT
                                                  const float*  __restrict__ bias,
                                                  float* __restrict__ out) {
    __shared__ float ldsf[2 * 20480] __attribute__((aligned(16)));  // 160 KiB

    const int tid  = threadIdx.x;
    const int lane = tid & 63;
    const int wid  = tid >> 6;          // 0..7
    const int wm   = wid >> 1;          // 0..3  (64-row strip)
    const int wn   = wid & 1;           // 0..1  (64-col strip)
    const int l15  = lane & 15;
    const int lg   = lane >> 4;

    // XCD swizzle: xcd gets 8 contiguous m-panels x all 8 n-tiles
    const int bid = blockIdx.x;               // 0..511
    const int xcd = bid & 7, i2 = bid >> 3;   // i2 0..63
    const int nt  = i2 & 7;                   // 8 n-tiles (BN=128)
    const int mt  = xcd * 8 + (i2 >> 3);      // 64 m-tiles (BM=256)
    const int m0  = mt * 256, n0 = nt * 128;

    // A staging: slot s = i*512+tid -> row s>>4, phys chunk s&15
    const int sArow   = tid >> 4;             // 0..31 (+32 per i)
    const int sAchunk = (tid & 15) ^ ((tid >> 4) & 15);
    const float* pA = A + (size_t)(m0 + sArow) * 256 + sAchunk * 4;

    // B staging: slot s = j*512+tid -> row s>>3, phys chunk s&7
    const int sBrow   = tid >> 3;             // 0..63 (+64 per j)
    const int sBchunk = (tid & 7) ^ ((tid >> 3) & 7);
    const _Float16* gB = Bt + (size_t)(n0 + sBrow) * 1024 + sBchunk * 8;

    // A fragment read: row = wm*64 + F*16 + l15 (row&15 == l15);
    // chunk(kq,c) = (kq*8 + lg*2 + c) ^ l15   (f32 units, row = 64 f32)
    const int aRowBase = (wm * 64 + l15) * 64;
    const int ac00 = ((lg * 2)     ^ l15) * 4;
    const int ac01 = ((lg * 2 + 1) ^ l15) * 4;
    const int ac10 = ((8 + lg * 2)     ^ l15) * 4;
    const int ac11 = ((8 + lg * 2 + 1) ^ l15) * 4;

    // B fragment read: row = wn*64 + F*16 + l15 (row&7 == l15&7);
    // chunk(kq) = (kq*4 + lg) ^ (l15&7)       (f16 units, row = 64 f16)
    const int bRowBase = (wn * 64 + l15) * 64;
    const int bc0 = ((lg)     ^ (l15 & 7)) * 8;
    const int bc1 = ((4 + lg) ^ (l15 & 7)) * 8;

    f32x4 acc[4][4] = {};

    // prologue: stage tile 0 into buffer 0, cold drain
    ISSUE_A(0, 0);  STAGE_B(0, 0);
    VMW(0);
    BARRIER();

    for (int t = 0; t < 15; ++t) {
        TILE(t, 1, VMW(0));
    }
    TILE(15, 0, (void)0);

    // epilogue: C/D layout col=lane&15, row=(lane>>4)*4+rr
    const int kb   = nt >> 1;                          // output blade
    const int ucol = (nt & 1) * 128 + wn * 64 + l15;   // col within blade
    float bv[4];
#pragma unroll
    for (int fn = 0; fn < 4; ++fn)
        bv[fn] = bias[nt * 128 + wn * 64 + fn * 16 + l15];
#pragma unroll
    for (int fm = 0; fm < 4; ++fm) {
        const int m = m0 + wm * 64 + fm * 16 + lg * 4;
#pragma unroll
        for (int rr = 0; rr < 4; ++rr) {
            float* op = out + ((size_t)kb * 16384 + m + rr) * 256 + ucol;
#pragma unroll
            for (int fn = 0; fn < 4; ++fn)
                op[fn * 16] = acc[fm][fn][rr] + bv[fn];
        }
    }
}

// ---------------------------------------------------------------------------
extern "C" void kernel_launch(void* const* d_in, const int* in_sizes, int n_in,
                              void* d_out, int out_size, void* d_ws, size_t ws_size,
                              hipStream_t stream) {
    (void)in_sizes; (void)n_in; (void)out_size; (void)ws_size;
    const float* x = (const float*)d_in[0];   // (65536, 256)
    const float* W = (const float*)d_in[1];   // (256, 1024)
    const float* b = (const float*)d_in[2];   // (1024,)
    float* out = (float*)d_out;               // (65536, 256)

    _Float16* Wt = (_Float16*)d_ws;           // 2 MB

    build_wcatT<<<4096, 256, 0, stream>>>(W, Wt);
    ga_gemm<<<512, 512, 0, stream>>>(x, Wt, b, out);
}